// Round 1
// baseline (4351.203 us; speedup 1.0000x reference)
//
#include <hip/hip_runtime.h>
#include <math.h>

#define N_NODES 100000
#define BN_EPS 1e-5f

// ---------------------------------------------------------------------------
// stats buffer: 3 layers x (64 sum + 64 sumsq) = 384 floats
__global__ void zero_stats_k(float* stats) {
    int t = threadIdx.x;
    if (t < 384) stats[t] = 0.f;
}

// agg[i] = (1 + eps) * x[i]   (element-group-of-4 per thread)
__global__ void init_agg_k(const float* __restrict__ x, const float* __restrict__ epsp,
                           float* __restrict__ agg, int n4) {
    int gid = blockIdx.x * blockDim.x + threadIdx.x;
    if (gid >= n4) return;
    float e = 1.0f + *epsp;
    float4 v = reinterpret_cast<const float4*>(x)[gid];
    v.x *= e; v.y *= e; v.z *= e; v.w *= e;
    reinterpret_cast<float4*>(agg)[gid] = v;
}

// agg[dst[e]] += x[src[e]] ; 16 threads per edge, 4 channels each
__global__ void scatter_add_k(const int* __restrict__ ei, const float* __restrict__ x,
                              float* __restrict__ agg, int E) {
    int gid = blockIdx.x * blockDim.x + threadIdx.x;
    int e = gid >> 4, cg = gid & 15;
    if (e >= E) return;
    int s = ei[e];
    int d = ei[E + e];
    float4 v = reinterpret_cast<const float4*>(x + (size_t)s * 64)[cg];
    float* a = agg + (size_t)d * 64 + cg * 4;
    atomicAdd(a + 0, v.x);
    atomicAdd(a + 1, v.y);
    atomicAdd(a + 2, v.z);
    atomicAdd(a + 3, v.w);
}

// In-place h = relu(h @ w + b) over a 64-row tile; optional BN stats accum.
template <bool STATS>
__global__ __launch_bounds__(256) void gemm64_relu_k(float* __restrict__ h,
                                                     const float* __restrict__ w,
                                                     const float* __restrict__ b,
                                                     float* __restrict__ stats,
                                                     int nrows) {
    __shared__ float xs[64][68];     // transposed x tile: xs[k][r], pad keeps 16B align
    __shared__ float wsh[64 * 64];
    __shared__ float bsh[64];
    __shared__ float sred[128];

    int tid = threadIdx.x;
    int r0 = blockIdx.x * 64;

    // stage weights (4096 floats = 1024 float4)
    const float4* w4 = reinterpret_cast<const float4*>(w);
    float4* wsh4 = reinterpret_cast<float4*>(wsh);
#pragma unroll
    for (int i = 0; i < 4; ++i) wsh4[tid + i * 256] = w4[tid + i * 256];
    if (tid < 64) bsh[tid] = b[tid];
    if (STATS && tid < 128) sred[tid] = 0.f;

    // stage x tile transposed (coalesced float4 reads, scalar LDS writes)
    {
        int rr = tid >> 4;   // 0..15
        int k4 = tid & 15;   // float4 column
#pragma unroll
        for (int i = 0; i < 4; ++i) {
            int r = rr + i * 16;
            float4 v;
            if (r0 + r < nrows)
                v = reinterpret_cast<const float4*>(h + (size_t)(r0 + r) * 64)[k4];
            else
                v = make_float4(0.f, 0.f, 0.f, 0.f);
            xs[k4 * 4 + 0][r] = v.x;
            xs[k4 * 4 + 1][r] = v.y;
            xs[k4 * 4 + 2][r] = v.z;
            xs[k4 * 4 + 3][r] = v.w;
        }
    }
    __syncthreads();

    int tr = tid & 15, tc = tid >> 4;
    int r = tr * 4, c = tc * 4;
    float acc[4][4];
#pragma unroll
    for (int i = 0; i < 4; ++i)
#pragma unroll
        for (int j = 0; j < 4; ++j) acc[i][j] = 0.f;

#pragma unroll 8
    for (int k = 0; k < 64; ++k) {
        float4 xv = *reinterpret_cast<const float4*>(&xs[k][r]);
        float4 wv = *reinterpret_cast<const float4*>(&wsh[k * 64 + c]);
        float xa[4] = {xv.x, xv.y, xv.z, xv.w};
        float wa[4] = {wv.x, wv.y, wv.z, wv.w};
#pragma unroll
        for (int i = 0; i < 4; ++i)
#pragma unroll
            for (int j = 0; j < 4; ++j) acc[i][j] = fmaf(xa[i], wa[j], acc[i][j]);
    }

    // bias + relu
#pragma unroll
    for (int j = 0; j < 4; ++j) {
        float bj = bsh[c + j];
#pragma unroll
        for (int i = 0; i < 4; ++i) acc[i][j] = fmaxf(acc[i][j] + bj, 0.f);
    }

    // in-place store (block staged its whole tile already)
#pragma unroll
    for (int i = 0; i < 4; ++i) {
        int row = r0 + r + i;
        if (row < nrows) {
            float4 o = make_float4(acc[i][0], acc[i][1], acc[i][2], acc[i][3]);
            *reinterpret_cast<float4*>(h + (size_t)row * 64 + c) = o;
        }
    }

    if (STATS) {
#pragma unroll
        for (int j = 0; j < 4; ++j) {
            float s = 0.f, q = 0.f;
#pragma unroll
            for (int i = 0; i < 4; ++i) {
                if (r0 + r + i < nrows) {
                    s += acc[i][j];
                    q += acc[i][j] * acc[i][j];
                }
            }
            atomicAdd(&sred[c + j], s);
            atomicAdd(&sred[64 + c + j], q);
        }
        __syncthreads();
        if (tid < 128) atomicAdd(&stats[tid], sred[tid]);
    }
}

// out = relu( (h - mean) * rsqrt(var+eps) * g + bt )
__global__ void bn_apply_k(const float* __restrict__ h, const float* __restrict__ stats,
                           const float* __restrict__ g, const float* __restrict__ bt,
                           float* __restrict__ out, int n4, float invn) {
    __shared__ float ssc[64], sof[64];
    int tid = threadIdx.x;
    if (tid < 64) {
        float mean = stats[tid] * invn;
        float var = stats[64 + tid] * invn - mean * mean;
        float sc = g[tid] * rsqrtf(var + BN_EPS);
        ssc[tid] = sc;
        sof[tid] = bt[tid] - mean * sc;
    }
    __syncthreads();
    int gid = blockIdx.x * blockDim.x + tid;
    if (gid >= n4) return;
    int c = (gid & 15) * 4;
    float4 v = reinterpret_cast<const float4*>(h)[gid];
    v.x = fmaxf(fmaf(v.x, ssc[c + 0], sof[c + 0]), 0.f);
    v.y = fmaxf(fmaf(v.y, ssc[c + 1], sof[c + 1]), 0.f);
    v.z = fmaxf(fmaf(v.z, ssc[c + 2], sof[c + 2]), 0.f);
    v.w = fmaxf(fmaf(v.w, ssc[c + 3], sof[c + 3]), 0.f);
    reinterpret_cast<float4*>(out)[gid] = v;
}

// out[N x 16] = x[N x 64] @ wl[64 x 16] + bl
__global__ __launch_bounds__(256) void final_linear_k(const float* __restrict__ x,
                                                      const float* __restrict__ wl,
                                                      const float* __restrict__ bl,
                                                      float* __restrict__ out, int nrows) {
    __shared__ float xs[64][68];
    __shared__ float wsh[64 * 16];
    __shared__ float bsh[16];
    int tid = threadIdx.x;
    int r0 = blockIdx.x * 64;

    reinterpret_cast<float4*>(wsh)[tid] = reinterpret_cast<const float4*>(wl)[tid];  // 256 f4
    if (tid < 16) bsh[tid] = bl[tid];
    {
        int rr = tid >> 4, k4 = tid & 15;
#pragma unroll
        for (int i = 0; i < 4; ++i) {
            int r = rr + i * 16;
            float4 v;
            if (r0 + r < nrows)
                v = reinterpret_cast<const float4*>(x + (size_t)(r0 + r) * 64)[k4];
            else
                v = make_float4(0.f, 0.f, 0.f, 0.f);
            xs[k4 * 4 + 0][r] = v.x;
            xs[k4 * 4 + 1][r] = v.y;
            xs[k4 * 4 + 2][r] = v.z;
            xs[k4 * 4 + 3][r] = v.w;
        }
    }
    __syncthreads();

    int tc = tid & 3, r = tid >> 2;  // r: 0..63
    int c = tc * 4;
    float acc0 = 0.f, acc1 = 0.f, acc2 = 0.f, acc3 = 0.f;
#pragma unroll 8
    for (int k = 0; k < 64; ++k) {
        float xv = xs[k][r];
        float4 wv = *reinterpret_cast<const float4*>(&wsh[k * 16 + c]);
        acc0 = fmaf(xv, wv.x, acc0);
        acc1 = fmaf(xv, wv.y, acc1);
        acc2 = fmaf(xv, wv.z, acc2);
        acc3 = fmaf(xv, wv.w, acc3);
    }
    int row = r0 + r;
    if (row < nrows) {
        float4 o = make_float4(acc0 + bsh[c], acc1 + bsh[c + 1], acc2 + bsh[c + 2], acc3 + bsh[c + 3]);
        *reinterpret_cast<float4*>(out + (size_t)row * 16 + c) = o;
    }
}

// ---------------------------------------------------------------------------
extern "C" void kernel_launch(void* const* d_in, const int* in_sizes, int n_in,
                              void* d_out, int out_size, void* d_ws, size_t ws_size,
                              hipStream_t stream) {
    const float* x = (const float*)d_in[0];
    const int* ei = (const int*)d_in[1];
    const int E = in_sizes[1] / 2;

    const float* eps[3] = {(const float*)d_in[2], (const float*)d_in[9], (const float*)d_in[16]};
    const float* w1[3]  = {(const float*)d_in[3], (const float*)d_in[10], (const float*)d_in[17]};
    const float* b1[3]  = {(const float*)d_in[4], (const float*)d_in[11], (const float*)d_in[18]};
    const float* w2[3]  = {(const float*)d_in[5], (const float*)d_in[12], (const float*)d_in[19]};
    const float* b2[3]  = {(const float*)d_in[6], (const float*)d_in[13], (const float*)d_in[20]};
    const float* g[3]   = {(const float*)d_in[7], (const float*)d_in[14], (const float*)d_in[21]};
    const float* bt[3]  = {(const float*)d_in[8], (const float*)d_in[15], (const float*)d_in[22]};
    const float* wl = (const float*)d_in[23];
    const float* bl = (const float*)d_in[24];

    float* agg   = (float*)d_ws;
    float* xcur  = agg + (size_t)N_NODES * 64;
    float* stats = xcur + (size_t)N_NODES * 64;

    const int n4 = N_NODES * 16;                 // float4 groups per N x 64 array
    const int nblk4 = (n4 + 255) / 256;          // 6250
    const int gemmblk = (N_NODES + 63) / 64;     // 1563
    const int scatblk = (E * 16 + 255) / 256;    // 100000
    const float invn = 1.0f / (float)N_NODES;

    zero_stats_k<<<1, 384, 0, stream>>>(stats);

    const float* xin = x;
    for (int L = 0; L < 3; ++L) {
        init_agg_k<<<nblk4, 256, 0, stream>>>(xin, eps[L], agg, n4);
        scatter_add_k<<<scatblk, 256, 0, stream>>>(ei, xin, agg, E);
        gemm64_relu_k<false><<<gemmblk, 256, 0, stream>>>(agg, w1[L], b1[L], nullptr, N_NODES);
        gemm64_relu_k<true><<<gemmblk, 256, 0, stream>>>(agg, w2[L], b2[L], stats + L * 128, N_NODES);
        bn_apply_k<<<nblk4, 256, 0, stream>>>(agg, stats + L * 128, g[L], bt[L], xcur, n4, invn);
        xin = xcur;
    }
    final_linear_k<<<gemmblk, 256, 0, stream>>>(xcur, wl, bl, (float*)d_out, N_NODES);
}

// Round 2
// 685.294 us; speedup vs baseline: 6.3494x; 6.3494x over previous
//
#include <hip/hip_runtime.h>
#include <math.h>

#define N_NODES 100000
#define BN_EPS 1e-5f

// ---------------------------------------------------------------------------
__global__ void zero_ints_k(int* p, int n) {
    int gid = blockIdx.x * blockDim.x + threadIdx.x;
    if (gid < n) p[gid] = 0;
}

__global__ void zero_stats_k(float* stats) {
    int t = threadIdx.x;
    if (t < 384) stats[t] = 0.f;
}

// deg[dst[e]]++ over all edges
__global__ void hist_k(const int* __restrict__ ei, int* __restrict__ deg, int E) {
    int e = blockIdx.x * blockDim.x + threadIdx.x;
    if (e >= E) return;
    atomicAdd(&deg[ei[E + e]], 1);
}

// per-block (1024 elems) exclusive scan; block totals to bsum
__global__ __launch_bounds__(256) void scan1_k(const int* __restrict__ deg, int* __restrict__ out,
                                               int* __restrict__ bsum, int n) {
    __shared__ int tmp[256];
    int t = threadIdx.x;
    int base = blockIdx.x * 1024 + t * 4;
    int v[4];
    int s = 0;
#pragma unroll
    for (int j = 0; j < 4; ++j) {
        int idx = base + j;
        v[j] = (idx < n) ? deg[idx] : 0;
        s += v[j];
    }
    tmp[t] = s;
    __syncthreads();
    for (int off = 1; off < 256; off <<= 1) {
        int a = (t >= off) ? tmp[t - off] : 0;
        __syncthreads();
        tmp[t] += a;
        __syncthreads();
    }
    int run = tmp[t] - s;  // exclusive prefix of this thread's chunk
#pragma unroll
    for (int j = 0; j < 4; ++j) {
        int idx = base + j;
        if (idx < n) out[idx] = run;
        run += v[j];
    }
    if (t == 255) bsum[blockIdx.x] = tmp[255];
}

// serial scan of ~98 block sums (trivial)
__global__ void scan2_k(const int* __restrict__ bsum, int* __restrict__ bbase, int nb) {
    if (threadIdx.x == 0) {
        int run = 0;
        for (int b = 0; b < nb; ++b) {
            int t = bsum[b];
            bbase[b] = run;
            run += t;
        }
    }
}

__global__ void finalize_k(int* __restrict__ row_ptr, const int* __restrict__ bbase,
                           int* __restrict__ cursor, int n, int E) {
    int gid = blockIdx.x * blockDim.x + threadIdx.x;
    if (gid < n) {
        int v = row_ptr[gid] + bbase[gid >> 10];
        row_ptr[gid] = v;
        cursor[gid] = v;
    } else if (gid == n) {
        row_ptr[n] = E;
    }
}

__global__ void place_k(const int* __restrict__ ei, int* __restrict__ cursor,
                        int* __restrict__ csr_src, int E) {
    int e = blockIdx.x * blockDim.x + threadIdx.x;
    if (e >= E) return;
    int d = ei[E + e];
    int pos = atomicAdd(&cursor[d], 1);
    csr_src[pos] = ei[e];
}

// agg[n] = (1+eps)*x[n] + sum_{s in nbrs(n)} x[s]; 16 lanes per node, float4 each
__global__ __launch_bounds__(256) void gather_k(const float* __restrict__ x,
                                                const int* __restrict__ row_ptr,
                                                const int* __restrict__ csr_src,
                                                const float* __restrict__ epsp,
                                                float* __restrict__ agg, int n) {
    int tid = threadIdx.x;
    int node = blockIdx.x * 16 + (tid >> 4);
    if (node >= n) return;
    int cg = tid & 15;
    float e = 1.0f + *epsp;
    float4 acc = reinterpret_cast<const float4*>(x + (size_t)node * 64)[cg];
    acc.x *= e; acc.y *= e; acc.z *= e; acc.w *= e;
    int j = row_ptr[node], end = row_ptr[node + 1];
    for (; j < end; ++j) {
        int s = csr_src[j];
        float4 v = reinterpret_cast<const float4*>(x + (size_t)s * 64)[cg];
        acc.x += v.x; acc.y += v.y; acc.z += v.z; acc.w += v.w;
    }
    reinterpret_cast<float4*>(agg + (size_t)node * 64)[cg] = acc;
}

// In-place h = relu(h @ w + b) over a 64-row tile; optional BN stats accum.
template <bool STATS>
__global__ __launch_bounds__(256) void gemm64_relu_k(float* __restrict__ h,
                                                     const float* __restrict__ w,
                                                     const float* __restrict__ b,
                                                     float* __restrict__ stats,
                                                     int nrows) {
    __shared__ float xs[64][68];
    __shared__ float wsh[64 * 64];
    __shared__ float bsh[64];
    __shared__ float sred[128];

    int tid = threadIdx.x;
    int r0 = blockIdx.x * 64;

    const float4* w4 = reinterpret_cast<const float4*>(w);
    float4* wsh4 = reinterpret_cast<float4*>(wsh);
#pragma unroll
    for (int i = 0; i < 4; ++i) wsh4[tid + i * 256] = w4[tid + i * 256];
    if (tid < 64) bsh[tid] = b[tid];
    if (STATS && tid < 128) sred[tid] = 0.f;

    {
        int rr = tid >> 4;
        int k4 = tid & 15;
#pragma unroll
        for (int i = 0; i < 4; ++i) {
            int r = rr + i * 16;
            float4 v;
            if (r0 + r < nrows)
                v = reinterpret_cast<const float4*>(h + (size_t)(r0 + r) * 64)[k4];
            else
                v = make_float4(0.f, 0.f, 0.f, 0.f);
            xs[k4 * 4 + 0][r] = v.x;
            xs[k4 * 4 + 1][r] = v.y;
            xs[k4 * 4 + 2][r] = v.z;
            xs[k4 * 4 + 3][r] = v.w;
        }
    }
    __syncthreads();

    int tr = tid & 15, tc = tid >> 4;
    int r = tr * 4, c = tc * 4;
    float acc[4][4];
#pragma unroll
    for (int i = 0; i < 4; ++i)
#pragma unroll
        for (int j = 0; j < 4; ++j) acc[i][j] = 0.f;

#pragma unroll 8
    for (int k = 0; k < 64; ++k) {
        float4 xv = *reinterpret_cast<const float4*>(&xs[k][r]);
        float4 wv = *reinterpret_cast<const float4*>(&wsh[k * 64 + c]);
        float xa[4] = {xv.x, xv.y, xv.z, xv.w};
        float wa[4] = {wv.x, wv.y, wv.z, wv.w};
#pragma unroll
        for (int i = 0; i < 4; ++i)
#pragma unroll
            for (int j = 0; j < 4; ++j) acc[i][j] = fmaf(xa[i], wa[j], acc[i][j]);
    }

#pragma unroll
    for (int j = 0; j < 4; ++j) {
        float bj = bsh[c + j];
#pragma unroll
        for (int i = 0; i < 4; ++i) acc[i][j] = fmaxf(acc[i][j] + bj, 0.f);
    }

#pragma unroll
    for (int i = 0; i < 4; ++i) {
        int row = r0 + r + i;
        if (row < nrows) {
            float4 o = make_float4(acc[i][0], acc[i][1], acc[i][2], acc[i][3]);
            *reinterpret_cast<float4*>(h + (size_t)row * 64 + c) = o;
        }
    }

    if (STATS) {
#pragma unroll
        for (int j = 0; j < 4; ++j) {
            float s = 0.f, q = 0.f;
#pragma unroll
            for (int i = 0; i < 4; ++i) {
                if (r0 + r + i < nrows) {
                    s += acc[i][j];
                    q += acc[i][j] * acc[i][j];
                }
            }
            atomicAdd(&sred[c + j], s);
            atomicAdd(&sred[64 + c + j], q);
        }
        __syncthreads();
        if (tid < 128) atomicAdd(&stats[tid], sred[tid]);
    }
}

// out = relu( (h - mean) * rsqrt(var+eps) * g + bt )
__global__ void bn_apply_k(const float* __restrict__ h, const float* __restrict__ stats,
                           const float* __restrict__ g, const float* __restrict__ bt,
                           float* __restrict__ out, int n4, float invn) {
    __shared__ float ssc[64], sof[64];
    int tid = threadIdx.x;
    if (tid < 64) {
        float mean = stats[tid] * invn;
        float var = stats[64 + tid] * invn - mean * mean;
        float sc = g[tid] * rsqrtf(var + BN_EPS);
        ssc[tid] = sc;
        sof[tid] = bt[tid] - mean * sc;
    }
    __syncthreads();
    int gid = blockIdx.x * blockDim.x + tid;
    if (gid >= n4) return;
    int c = (gid & 15) * 4;
    float4 v = reinterpret_cast<const float4*>(h)[gid];
    v.x = fmaxf(fmaf(v.x, ssc[c + 0], sof[c + 0]), 0.f);
    v.y = fmaxf(fmaf(v.y, ssc[c + 1], sof[c + 1]), 0.f);
    v.z = fmaxf(fmaf(v.z, ssc[c + 2], sof[c + 2]), 0.f);
    v.w = fmaxf(fmaf(v.w, ssc[c + 3], sof[c + 3]), 0.f);
    reinterpret_cast<float4*>(out)[gid] = v;
}

// out[N x 16] = x[N x 64] @ wl[64 x 16] + bl
__global__ __launch_bounds__(256) void final_linear_k(const float* __restrict__ x,
                                                      const float* __restrict__ wl,
                                                      const float* __restrict__ bl,
                                                      float* __restrict__ out, int nrows) {
    __shared__ float xs[64][68];
    __shared__ float wsh[64 * 16];
    __shared__ float bsh[16];
    int tid = threadIdx.x;
    int r0 = blockIdx.x * 64;

    reinterpret_cast<float4*>(wsh)[tid] = reinterpret_cast<const float4*>(wl)[tid];
    if (tid < 16) bsh[tid] = bl[tid];
    {
        int rr = tid >> 4, k4 = tid & 15;
#pragma unroll
        for (int i = 0; i < 4; ++i) {
            int r = rr + i * 16;
            float4 v;
            if (r0 + r < nrows)
                v = reinterpret_cast<const float4*>(x + (size_t)(r0 + r) * 64)[k4];
            else
                v = make_float4(0.f, 0.f, 0.f, 0.f);
            xs[k4 * 4 + 0][r] = v.x;
            xs[k4 * 4 + 1][r] = v.y;
            xs[k4 * 4 + 2][r] = v.z;
            xs[k4 * 4 + 3][r] = v.w;
        }
    }
    __syncthreads();

    int tc = tid & 3, r = tid >> 2;
    int c = tc * 4;
    float acc0 = 0.f, acc1 = 0.f, acc2 = 0.f, acc3 = 0.f;
#pragma unroll 8
    for (int k = 0; k < 64; ++k) {
        float xv = xs[k][r];
        float4 wv = *reinterpret_cast<const float4*>(&wsh[k * 16 + c]);
        acc0 = fmaf(xv, wv.x, acc0);
        acc1 = fmaf(xv, wv.y, acc1);
        acc2 = fmaf(xv, wv.z, acc2);
        acc3 = fmaf(xv, wv.w, acc3);
    }
    int row = r0 + r;
    if (row < nrows) {
        float4 o = make_float4(acc0 + bsh[c], acc1 + bsh[c + 1], acc2 + bsh[c + 2], acc3 + bsh[c + 3]);
        *reinterpret_cast<float4*>(out + (size_t)row * 16 + c) = o;
    }
}

// ---------------------------------------------------------------------------
extern "C" void kernel_launch(void* const* d_in, const int* in_sizes, int n_in,
                              void* d_out, int out_size, void* d_ws, size_t ws_size,
                              hipStream_t stream) {
    const float* x = (const float*)d_in[0];
    const int* ei = (const int*)d_in[1];
    const int E = in_sizes[1] / 2;

    const float* eps[3] = {(const float*)d_in[2], (const float*)d_in[9], (const float*)d_in[16]};
    const float* w1[3]  = {(const float*)d_in[3], (const float*)d_in[10], (const float*)d_in[17]};
    const float* b1[3]  = {(const float*)d_in[4], (const float*)d_in[11], (const float*)d_in[18]};
    const float* w2[3]  = {(const float*)d_in[5], (const float*)d_in[12], (const float*)d_in[19]};
    const float* b2[3]  = {(const float*)d_in[6], (const float*)d_in[13], (const float*)d_in[20]};
    const float* g[3]   = {(const float*)d_in[7], (const float*)d_in[14], (const float*)d_in[21]};
    const float* bt[3]  = {(const float*)d_in[8], (const float*)d_in[15], (const float*)d_in[22]};
    const float* wl = (const float*)d_in[23];
    const float* bl = (const float*)d_in[24];

    // workspace layout
    float* agg   = (float*)d_ws;
    float* xcur  = agg + (size_t)N_NODES * 64;
    float* stats = xcur + (size_t)N_NODES * 64;
    int* row_ptr = (int*)(stats + 384);
    int* cursor  = row_ptr + (N_NODES + 1);
    int* deg     = cursor + N_NODES;
    int* bsum    = deg + N_NODES;
    int* bbase   = bsum + 128;
    int* csr_ws  = bbase + 128;
    size_t used  = (size_t)((char*)csr_ws - (char*)d_ws);
    // csr_src: ws if it fits, else use d_out as scratch (out_size*4 == E*4)
    int* csr_src = (used + (size_t)E * 4 <= ws_size) ? csr_ws : (int*)d_out;

    const int n4 = N_NODES * 16;
    const int nblk4 = (n4 + 255) / 256;
    const int gemmblk = (N_NODES + 63) / 64;
    const int eblk = (E + 255) / 256;
    const int nb_scan = (N_NODES + 1023) / 1024;
    const float invn = 1.0f / (float)N_NODES;

    // ---- CSR build (once; reused by all 3 layers) ----
    zero_ints_k<<<(N_NODES + 255) / 256, 256, 0, stream>>>(deg, N_NODES);
    zero_stats_k<<<1, 384, 0, stream>>>(stats);
    hist_k<<<eblk, 256, 0, stream>>>(ei, deg, E);
    scan1_k<<<nb_scan, 256, 0, stream>>>(deg, row_ptr, bsum, N_NODES);
    scan2_k<<<1, 64, 0, stream>>>(bsum, bbase, nb_scan);
    finalize_k<<<(N_NODES + 256) / 256, 256, 0, stream>>>(row_ptr, bbase, cursor, N_NODES, E);
    place_k<<<eblk, 256, 0, stream>>>(ei, cursor, csr_src, E);

    // ---- 3 GIN layers ----
    const float* xin = x;
    for (int L = 0; L < 3; ++L) {
        gather_k<<<(N_NODES + 15) / 16, 256, 0, stream>>>(xin, row_ptr, csr_src, eps[L], agg, N_NODES);
        gemm64_relu_k<false><<<gemmblk, 256, 0, stream>>>(agg, w1[L], b1[L], nullptr, N_NODES);
        gemm64_relu_k<true><<<gemmblk, 256, 0, stream>>>(agg, w2[L], b2[L], stats + L * 128, N_NODES);
        bn_apply_k<<<nblk4, 256, 0, stream>>>(agg, stats + L * 128, g[L], bt[L], xcur, n4, invn);
        xin = xcur;
    }
    final_linear_k<<<gemmblk, 256, 0, stream>>>(xcur, wl, bl, (float*)d_out, N_NODES);
}